// Round 5
// baseline (243.980 us; speedup 1.0000x reference)
//
#include <hip/hip_runtime.h>
#include <math.h>

#define BSZ   2
#define TSEQ  2048
#define CDIM  1024
#define NHEAD 16
#define HDIM  64
#define BT    (BSZ*TSEQ)
#define NQKV  1152   // 1024 q + 64 k + 64 v

typedef __attribute__((ext_vector_type(8))) short short8;
typedef __attribute__((ext_vector_type(4))) float f32x4;
typedef unsigned short u16;
typedef unsigned int   u32;

__device__ __forceinline__ u16 f2b(float f) {
    union { float f; u32 u; } c; c.f = f;
    u32 u = c.u;
    u += 0x7fffu + ((u >> 16) & 1u);   // round-nearest-even
    return (u16)(u >> 16);
}
__device__ __forceinline__ u32 pack2(float lo, float hi) {
    return (u32)f2b(lo) | ((u32)f2b(hi) << 16);
}

// async global->LDS, 16B per lane. LDS dest must be wave-uniform base + lane*16.
__device__ __forceinline__ void async_copy16(const void* g, void* l) {
    __builtin_amdgcn_global_load_lds(
        (__attribute__((address_space(1))) const void*)g,
        (__attribute__((address_space(3))) void*)l,
        16, 0, 0);
}

// ---------------------------------------------------------------------------
__global__ __launch_bounds__(256) void cast_bf16_kernel(
    const float* __restrict__ src, u16* __restrict__ dst, int n4)
{
    int i = blockIdx.x * 256 + threadIdx.x;
    if (i >= n4) return;
    float4 f = ((const float4*)src)[i];
    u16* d = dst + (size_t)i * 4;
    d[0] = f2b(f.x); d[1] = f2b(f.y); d[2] = f2b(f.z); d[3] = f2b(f.w);
}

// W [K][Nw] fp32 -> Wt [nofs+n][K] bf16 (transpose + cast)
__global__ __launch_bounds__(256) void transpose_cast_kernel(
    const float* __restrict__ W, u16* __restrict__ Wt,
    int K, int Nw, int nofs)
{
    __shared__ float T[64][65];
    const int tid = threadIdx.x;
    const int k0 = blockIdx.y * 64, n0 = blockIdx.x * 64;
    #pragma unroll
    for (int i = 0; i < 16; ++i) {
        int idx = i * 256 + tid, r = idx >> 6, c = idx & 63;
        T[r][c] = W[(size_t)(k0 + r) * Nw + n0 + c];
    }
    __syncthreads();
    #pragma unroll
    for (int i = 0; i < 16; ++i) {
        int idx = i * 256 + tid, rn = idx >> 6, ck = idx & 63;
        Wt[(size_t)(nofs + n0 + rn) * K + k0 + ck] = f2b(T[ck][rn]);
    }
}

__global__ __launch_bounds__(256) void concat_bias3_kernel(
    const float* __restrict__ bq, const float* __restrict__ bk,
    const float* __restrict__ bv, float* __restrict__ bqkv)
{
    int i = blockIdx.x * 256 + threadIdx.x;
    if (i >= NQKV) return;
    bqkv[i] = (i < 1024) ? bq[i] : (i < 1088 ? bk[i - 1024] : bv[i - 1088]);
}

// ---------------------------------------------------------------------------
// Y[M][N] fp32 = A[M][K](bf16) @ Bt[N][K](bf16)^T + bias.
// 64x128 tile, BK=64: 16 MFMAs per wave per barrier-pair (m97 density).
// Chunk-ordered LDS: chunk ca -> row=(ca>>7)*16+(ca&15),
// koff=((ca>>6)&1)*32+((ca>>4)&3)*8. Staging dest lane-linear (HW req) AND
// frag ds_read_b128 lane-linear (conflict-free).
// ---------------------------------------------------------------------------
__global__ __launch_bounds__(256) void gemm_mfma_kernel(
    const u16* __restrict__ A, const u16* __restrict__ Bt,
    const float* __restrict__ bias, float* __restrict__ Y,
    int M, int N, int K)
{
    __shared__ __align__(16) u16 AsC[64 * 64];    //  8 KB, 512 chunks
    __shared__ __align__(16) u16 BsC[128 * 64];   // 16 KB, 1024 chunks
    const int tid  = threadIdx.x;
    const int wave = tid >> 6, lane = tid & 63;
    const int ln16 = lane & 15, quad = lane >> 4;
    const int wm = wave >> 1, wn = wave & 1;
    const int m0 = blockIdx.y * 64, n0 = blockIdx.x * 128;

    const u16* ag[2]; u16* al[2];
    #pragma unroll
    for (int n = 0; n < 2; ++n) {
        int ca = tid + n * 256;
        int row = ((ca >> 7) << 4) | (ca & 15);
        int koff = ((ca >> 6) & 1) * 32 + ((ca >> 4) & 3) * 8;
        ag[n] = A + (size_t)(m0 + row) * K + koff;
        al[n] = AsC + ca * 8;
    }
    const u16* bg[4]; u16* bl[4];
    #pragma unroll
    for (int n = 0; n < 4; ++n) {
        int ca = tid + n * 256;
        int row = ((ca >> 7) << 4) | (ca & 15);
        int koff = ((ca >> 6) & 1) * 32 + ((ca >> 4) & 3) * 8;
        bg[n] = Bt + (size_t)(n0 + row) * K + koff;
        bl[n] = BsC + ca * 8;
    }

    f32x4 acc[2][4];
    #pragma unroll
    for (int i = 0; i < 2; ++i)
        #pragma unroll
        for (int j = 0; j < 4; ++j) acc[i][j] = (f32x4){0.f, 0.f, 0.f, 0.f};

    for (int k0 = 0; k0 < K; k0 += 64) {
        #pragma unroll
        for (int n = 0; n < 2; ++n) { async_copy16(ag[n], al[n]); ag[n] += 64; }
        #pragma unroll
        for (int n = 0; n < 4; ++n) { async_copy16(bg[n], bl[n]); bg[n] += 64; }
        __syncthreads();

        #pragma unroll
        for (int ks = 0; ks < 2; ++ks) {
            short8 af[2], bf[4];
            #pragma unroll
            for (int mt = 0; mt < 2; ++mt)
                af[mt] = *(const short8*)
                    &AsC[(((wm * 2 + mt) * 128) + ks * 64 + quad * 16 + ln16) * 8];
            #pragma unroll
            for (int nt = 0; nt < 4; ++nt)
                bf[nt] = *(const short8*)
                    &BsC[(((wn * 4 + nt) * 128) + ks * 64 + quad * 16 + ln16) * 8];
            #pragma unroll
            for (int mt = 0; mt < 2; ++mt)
                #pragma unroll
                for (int nt = 0; nt < 4; ++nt)
                    acc[mt][nt] = __builtin_amdgcn_mfma_f32_16x16x32_bf16(
                        af[mt], bf[nt], acc[mt][nt], 0, 0, 0);
        }
        __syncthreads();
    }

    #pragma unroll
    for (int mt = 0; mt < 2; ++mt)
        #pragma unroll
        for (int nt = 0; nt < 4; ++nt) {
            int n = n0 + wn * 64 + nt * 16 + ln16;
            float bb = bias[n];
            #pragma unroll
            for (int r = 0; r < 4; ++r) {
                int m = m0 + wm * 32 + mt * 16 + quad * 4 + r;
                Y[(size_t)m * N + n] = acc[mt][nt][r] + bb;
            }
        }
}

// ---------------------------------------------------------------------------
// RoPE for q (heads 0..15 -> qb, pre-scaled 1/8) and k (slot 16 -> kb), bf16.
// ---------------------------------------------------------------------------
__global__ __launch_bounds__(256) void rope_qk_kernel(
    const float* __restrict__ qkvf, u16* __restrict__ qb, u16* __restrict__ kb)
{
    int idx = blockIdx.x * 256 + threadIdx.x;
    const int total = BT * 17 * 16;
    if (idx >= total) return;
    int p4  = idx & 15;
    int rest = idx >> 4;
    int hh  = rest % 17;
    int bt  = rest / 17;
    int j   = p4 * 2;
    int tpos = bt & (TSEQ - 1);
    float f0 = exp2f(-0.41524101186092029f * (float)j);        // 10000^(-j/32)
    float f1 = exp2f(-0.41524101186092029f * (float)(j + 1));
    float a0s, a0c, a1s, a1c;
    __sincosf((float)tpos * f0, &a0s, &a0c);
    __sincosf((float)tpos * f1, &a1s, &a1c);
    const float* base = qkvf + (size_t)bt * NQKV + hh * 64;
    float t10 = base[j],      t11 = base[j + 1];
    float t20 = base[j + 32], t21 = base[j + 33];
    float lo0 = fmaf(t10, a0c, t20 * a0s), lo1 = fmaf(t11, a1c, t21 * a1s);
    float hi0 = fmaf(t10, a0s, -t20 * a0c), hi1 = fmaf(t11, a1s, -t21 * a1c);
    if (hh < 16) {   // q: scale by 1/8 (exact pow2; folds softmax 1/sqrt(64))
        u16* o = qb + (size_t)bt * CDIM + hh * 64 + j;
        *(u32*)o        = pack2(lo0 * 0.125f, lo1 * 0.125f);
        *(u32*)(o + 32) = pack2(hi0 * 0.125f, hi1 * 0.125f);
    } else {         // k
        u16* o = kb + (size_t)bt * HDIM + j;
        *(u32*)o        = pack2(lo0, lo1);
        *(u32*)(o + 32) = pack2(hi0, hi1);
    }
}

// ---------------------------------------------------------------------------
// v slice of qkvf [bt][1088+d] fp32 -> vT [b][d][T] bf16 (64x64 LDS tile)
// ---------------------------------------------------------------------------
__global__ __launch_bounds__(256) void transpose_v_kernel(
    const float* __restrict__ qkvf, u16* __restrict__ vT)
{
    __shared__ float T[64][65];
    const int tid = threadIdx.x;
    const int b  = blockIdx.y;
    const int t0 = blockIdx.x * 64;
    #pragma unroll
    for (int i = 0; i < 16; ++i) {
        int idx = i * 256 + tid, r = idx >> 6, c = idx & 63;
        T[r][c] = qkvf[(size_t)(b * TSEQ + t0 + r) * NQKV + 1088 + c];
    }
    __syncthreads();
    #pragma unroll
    for (int i = 0; i < 8; ++i) {
        int idx = i * 256 + tid;           // 0..2047  (uint pairs)
        int d = idx >> 5, tp = idx & 31;
        u32 u = pack2(T[tp * 2][d], T[tp * 2 + 1][d]);
        *(u32*)&vT[(size_t)(b * HDIM + d) * TSEQ + t0 + tp * 2] = u;
    }
}

// ---------------------------------------------------------------------------
// MFMA flash attention, balanced pairs + async bf16 staging (verified R4).
// Block p handles qt = p and qt = 31-p (exactly 33 k-tiles each).
// ---------------------------------------------------------------------------
__global__ __launch_bounds__(256) void flash_mfma_kernel(
    const u16* __restrict__ qb, const u16* __restrict__ kb,
    const u16* __restrict__ vT, u16* __restrict__ o)
{
    const int id = blockIdx.x;
    const int p  = id & 15;
    const int h  = (id >> 4) & 15;
    const int b  = id >> 8;
    __shared__ __align__(16) u16 Qs[512 * 8];        // 8 KB
    __shared__ __align__(16) u16 Ks[512 * 8];        // 8 KB
    __shared__ __align__(16) u16 Vs[512 * 8];        // 8 KB
    __shared__ __align__(16) u16 Ps[4 * 16 * 72];    // 9 KB, per-wave [16][72]

    const int tid  = threadIdx.x;
    const int wave = tid >> 6, lane = tid & 63;
    const int ln16 = lane & 15, quad = lane >> 4;

    const int c0 = tid;
    int row_c[2], off_c[2];
    #pragma unroll
    for (int hf = 0; hf < 2; ++hf) {
        int c = c0 + hf * 256;
        row_c[hf] = ((c >> 7) << 4) | (c & 15);
        off_c[hf] = ((c >> 6) & 1) * 32 + ((c >> 4) & 3) * 8;
    }

    u16* Pw = &Ps[wave * 16 * 72];

    for (int s = 0; s < 2; ++s) {
        const int qt = s ? (31 - p) : p;

        #pragma unroll
        for (int hf = 0; hf < 2; ++hf)
            async_copy16(
                qb + (size_t)(b * TSEQ + qt * 64 + row_c[hf]) * CDIM + h * HDIM + off_c[hf],
                Qs + (c0 + hf * 256) * 8);

        float m_r[4], l_r[4];
        f32x4 oacc[4];
        #pragma unroll
        for (int r = 0; r < 4; ++r) { m_r[r] = -1e30f; l_r[r] = 0.f; }
        #pragma unroll
        for (int t = 0; t < 4; ++t) oacc[t] = (f32x4){0.f, 0.f, 0.f, 0.f};

        for (int kt = 0; kt <= qt; ++kt) {
            const size_t kt0 = (size_t)(b * TSEQ + kt * 64);
            #pragma unroll
            for (int hf = 0; hf < 2; ++hf) {
                int cc = c0 + hf * 256;
                async_copy16(kb + (kt0 + row_c[hf]) * HDIM + off_c[hf], Ks + cc * 8);
                async_copy16(vT + (size_t)(b * HDIM + row_c[hf]) * TSEQ + kt * 64 + off_c[hf],
                             Vs + cc * 8);
            }
            __syncthreads();

            f32x4 sv[4];
            #pragma unroll
            for (int t = 0; t < 4; ++t) sv[t] = (f32x4){0.f, 0.f, 0.f, 0.f};
            #pragma unroll
            for (int kk2 = 0; kk2 < 2; ++kk2) {
                short8 af = *(const short8*)&Qs[(wave * 128 + kk2 * 64 + quad * 16 + ln16) * 8];
                #pragma unroll
                for (int t = 0; t < 4; ++t) {
                    short8 bf = *(const short8*)&Ks[(t * 128 + kk2 * 64 + quad * 16 + ln16) * 8];
                    sv[t] = __builtin_amdgcn_mfma_f32_16x16x32_bf16(af, bf, sv[t], 0, 0, 0);
                }
            }

            float sc[4][4];
            #pragma unroll
            for (int t = 0; t < 4; ++t)
                #pragma unroll
                for (int r = 0; r < 4; ++r) sc[t][r] = sv[t][r];
            if (kt == qt) {
                #pragma unroll
                for (int t = 0; t < 4; ++t) {
                    int key = t * 16 + ln16;
                    #pragma unroll
                    for (int r = 0; r < 4; ++r)
                        if (key > wave * 16 + quad * 4 + r) sc[t][r] = -1e30f;
                }
            }

            float alpha[4];
            #pragma unroll
            for (int r = 0; r < 4; ++r) {
                float mx = fmaxf(fmaxf(sc[0][r], sc[1][r]), fmaxf(sc[2][r], sc[3][r]));
                #pragma unroll
                for (int off = 1; off < 16; off <<= 1)
                    mx = fmaxf(mx, __shfl_xor(mx, off, 64));
                float mnew = fmaxf(m_r[r], mx);
                alpha[r] = __expf(m_r[r] - mnew);
                m_r[r] = mnew;
                float srow = 0.f;
                #pragma unroll
                for (int t = 0; t < 4; ++t) {
                    float e = __expf(sc[t][r] - mnew);
                    sc[t][r] = e;
                    srow += e;
                }
                #pragma unroll
                for (int off = 1; off < 16; off <<= 1)
                    srow += __shfl_xor(srow, off, 64);
                l_r[r] = l_r[r] * alpha[r] + srow;
            }

            #pragma unroll
            for (int t = 0; t < 4; ++t)
                #pragma unroll
                for (int r = 0; r < 4; ++r)
                    Pw[(quad * 4 + r) * 72 + t * 16 + ln16] = f2b(sc[t][r]);

            #pragma unroll
            for (int t = 0; t < 4; ++t)
                #pragma unroll
                for (int r = 0; r < 4; ++r)
                    oacc[t][r] *= alpha[r];

            #pragma unroll
            for (int kk2 = 0; kk2 < 2; ++kk2) {
                short8 pf = *(const short8*)&Pw[ln16 * 72 + kk2 * 32 + quad * 8];
                #pragma unroll
                for (int t = 0; t < 4; ++t) {
                    short8 vf = *(const short8*)&Vs[(t * 128 + kk2 * 64 + quad * 16 + ln16) * 8];
                    oacc[t] = __builtin_amdgcn_mfma_f32_16x16x32_bf16(pf, vf, oacc[t], 0, 0, 0);
                }
            }
            __syncthreads();
        }

        float inv[4];
        #pragma unroll
        for (int r = 0; r < 4; ++r) inv[r] = 1.0f / l_r[r];
        #pragma unroll
        for (int t = 0; t < 4; ++t) {
            #pragma unroll
            for (int r = 0; r < 4; ++r) {
                int row = qt * 64 + wave * 16 + quad * 4 + r;
                int d   = t * 16 + ln16;
                o[(size_t)(b * TSEQ + row) * CDIM + h * HDIM + d] = f2b(oacc[t][r] * inv[r]);
            }
        }
    }
}

// ---------------------------------------------------------------------------
extern "C" void kernel_launch(void* const* d_in, const int* in_sizes, int n_in,
                              void* d_out, int out_size, void* d_ws, size_t ws_size,
                              hipStream_t stream)
{
    const float* x  = (const float*)d_in[0];
    const float* Wq = (const float*)d_in[1];
    const float* bq = (const float*)d_in[2];
    const float* Wk = (const float*)d_in[3];
    const float* bk = (const float*)d_in[4];
    const float* Wv = (const float*)d_in[5];
    const float* bv = (const float*)d_in[6];
    const float* Wo = (const float*)d_in[7];
    const float* bo = (const float*)d_in[8];
    float* out = (float*)d_out;

    const size_t MB = 1u << 20;
    char* w = (char*)d_ws;
    u16*   xb   = (u16*)(w);                   //  8 MB [BT][1024] bf16
    u16*   qb   = (u16*)(w);                   //  alias (rope'd q, pre-scaled)
    float* qkvf = (float*)(w + 8 * MB);        // 18 MB [BT][1152] fp32
    u16*   aob  = (u16*)(w + 8 * MB);          //  alias, 8 MB [BT][1024] bf16
    u16*   Wqkvt= (u16*)(w + 26 * MB);         //  2.25 MB [1152][1024]
    u16*   Wot  = (u16*)(w + 29 * MB);         //  2 MB
    u16*   kb   = (u16*)(w + 31 * MB);         //  0.5 MB [BT][64]
    u16*   vT   = (u16*)(w + 31 * MB + 512 * 1024);   // 0.5 MB [B][64][T]
    float* bqkv = (float*)(w + 32 * MB);       //  4.5 KB

    dim3 blk(256);

    cast_bf16_kernel<<<dim3(BT * CDIM / 4 / 256), blk, 0, stream>>>(x, xb, BT * CDIM / 4);
    transpose_cast_kernel<<<dim3(16, 16), blk, 0, stream>>>(Wq, Wqkvt, CDIM, CDIM, 0);
    transpose_cast_kernel<<<dim3(1, 16),  blk, 0, stream>>>(Wk, Wqkvt, CDIM, HDIM, 1024);
    transpose_cast_kernel<<<dim3(1, 16),  blk, 0, stream>>>(Wv, Wqkvt, CDIM, HDIM, 1088);
    transpose_cast_kernel<<<dim3(16, 16), blk, 0, stream>>>(Wo, Wot, CDIM, CDIM, 0);
    concat_bias3_kernel<<<dim3(5), blk, 0, stream>>>(bq, bk, bv, bqkv);

    // fused q|k|v projection: [BT][1152]
    gemm_mfma_kernel<<<dim3(NQKV / 128, BT / 64), blk, 0, stream>>>(
        xb, Wqkvt, bqkv, qkvf, BT, NQKV, CDIM);

    // rope -> bf16 q (scaled 1/8) + bf16 k ; v transpose -> bf16 vT
    rope_qk_kernel<<<dim3(BT * 17 * 16 / 256), blk, 0, stream>>>(qkvf, qb, kb);
    transpose_v_kernel<<<dim3(TSEQ / 64, BSZ), blk, 0, stream>>>(qkvf, vT);

    // balanced flash attention -> aob (overwrites dead qkvf head)
    flash_mfma_kernel<<<dim3(16 * NHEAD * BSZ), blk, 0, stream>>>(qb, kb, vT, aob);

    // output projection
    gemm_mfma_kernel<<<dim3(CDIM / 128, BT / 64), blk, 0, stream>>>(
        aob, Wot, bo, out, BT, CDIM, CDIM);
}